// Round 1
// baseline (881.564 us; speedup 1.0000x reference)
//
#include <hip/hip_runtime.h>
#include <math.h>

// ---------------- problem constants ----------------
#define NTOK   1024      // B*T
#define EXP    16
#define TOPK   4
#define DMODEL 2048
#define DFFN   3584
#define HT_TILES 56      // DFFN/64
#define CT_TILES 32      // DMODEL/64

typedef __attribute__((ext_vector_type(8))) short bf16x8;
typedef __attribute__((ext_vector_type(4))) float f32x4;

// ---------------- workspace layout (bytes) ----------------
#define O_COUNTS 0
#define O_BASE   256
#define O_CURSOR 512
#define O_TOPI   4096
#define O_TOPW   (O_TOPI + 16384)
#define O_TOK    (O_TOPW + 16384)
#define O_WGT    (O_TOK + 16384)
#define O_SLOTNK (O_WGT + 16384)
#define O_HBUF   (O_SLOTNK + 16384)                 // bf16 [4096][DFFN]  = 29.36 MB
#define O_YPART  (O_HBUF + (size_t)4096*DFFN*2)     // bf16 [4096][DMODEL] = 16.78 MB
// total ~46.3 MB

__device__ __forceinline__ unsigned short f2b_rne(float f) {
  unsigned u = __builtin_bit_cast(unsigned, f);
  u += 0x7FFFu + ((u >> 16) & 1u);
  return (unsigned short)(u >> 16);
}
__device__ __forceinline__ float b2f(unsigned short h) {
  unsigned u = ((unsigned)h) << 16;
  return __builtin_bit_cast(float, u);
}

// store 4 fp32 -> 4 bf16 into LDS tile (row stride 64 bf16), XOR-swizzled at 16B granularity
__device__ __forceinline__ void st_bf16x4(unsigned short* lds, int row, int c4, float4 v) {
  unsigned long long p = (unsigned long long)f2b_rne(v.x)
    | ((unsigned long long)f2b_rne(v.y) << 16)
    | ((unsigned long long)f2b_rne(v.z) << 32)
    | ((unsigned long long)f2b_rne(v.w) << 48);
  *(unsigned long long*)(lds + row*64 + (((c4 >> 1) ^ (row & 7)) * 8) + (c4 & 1) * 4) = p;
}
// read one MFMA fragment (8 bf16 = 16B) from swizzled LDS tile
__device__ __forceinline__ bf16x8 ld_frag(const unsigned short* lds, int row, int chunk) {
  return *(const bf16x8*)(lds + row*64 + ((chunk ^ (row & 7)) * 8));
}

// ---------------- K0: zero counters ----------------
__global__ void k_zero(int* counts, int* cursor) {
  int t = threadIdx.x;
  if (t < EXP) { counts[t] = 0; cursor[t] = 0; }
}

// ---------------- K1: router (fp32, exact top-4 like lax.top_k) ----------------
__global__ void k_gate(const float* __restrict__ x, const float* __restrict__ gi,
                       int* __restrict__ topi, float* __restrict__ topw,
                       int* __restrict__ counts) {
  int n = blockIdx.x;
  int lane = threadIdx.x & 63, wave = threadIdx.x >> 6;
  __shared__ float lg[EXP];
  const float4* xr = (const float4*)(x + (size_t)n * DMODEL);
  #pragma unroll
  for (int i = 0; i < 4; ++i) {
    int e = wave * 4 + i;
    const float4* gr = (const float4*)(gi + (size_t)e * DMODEL);
    float s = 0.f;
    #pragma unroll
    for (int j = 0; j < 8; ++j) {
      float4 a = xr[j*64 + lane];
      float4 b = gr[j*64 + lane];
      s += a.x*b.x + a.y*b.y + a.z*b.z + a.w*b.w;
    }
    #pragma unroll
    for (int off = 32; off; off >>= 1) s += __shfl_xor(s, off);
    if (lane == 0) lg[e] = s;
  }
  __syncthreads();
  if (threadIdx.x == 0) {
    float v[EXP];
    #pragma unroll
    for (int j = 0; j < EXP; ++j) v[j] = lg[j];
    int bi[TOPK]; float bv[TOPK];
    #pragma unroll
    for (int k = 0; k < TOPK; ++k) {
      float best = -3.4e38f; int bidx = 0;
      for (int j = 0; j < EXP; ++j) if (v[j] > best) { best = v[j]; bidx = j; }
      bv[k] = best; bi[k] = bidx; v[bidx] = -3.4e38f;
    }
    float m = bv[0], ss = 0.f, w[TOPK];
    #pragma unroll
    for (int k = 0; k < TOPK; ++k) { w[k] = expf(bv[k] - m); ss += w[k]; }
    #pragma unroll
    for (int k = 0; k < TOPK; ++k) {
      topi[n*TOPK + k] = bi[k];
      topw[n*TOPK + k] = w[k] / ss;
      atomicAdd(&counts[bi[k]], 1);
    }
  }
}

// ---------------- K2: exclusive prefix over 16 counts ----------------
__global__ void k_prefix(const int* __restrict__ counts, int* __restrict__ basep) {
  if (threadIdx.x == 0) {
    int acc = 0;
    for (int e = 0; e < EXP; ++e) { basep[e] = acc; acc += counts[e]; }
  }
}

// ---------------- K3: scatter assignments into expert-sorted slots ----------------
__global__ void k_scatter(const int* __restrict__ topi, const float* __restrict__ topw,
                          const int* __restrict__ basep, int* __restrict__ cursor,
                          int* __restrict__ tok, float* __restrict__ wgt,
                          int* __restrict__ slotnk) {
  int n = blockIdx.x * blockDim.x + threadIdx.x;
  if (n >= NTOK) return;
  #pragma unroll
  for (int k = 0; k < TOPK; ++k) {
    int e = topi[n*TOPK + k];
    int pos = atomicAdd(&cursor[e], 1);
    int slot = basep[e] + pos;
    tok[slot] = n;
    wgt[slot] = topw[n*TOPK + k];
    slotnk[n*TOPK + k] = slot;
  }
}

// ---------------- K4: fused up+gate GEMM + SiLU (h = silu(g)*u*gate_w, bf16) -------
// grid: e*HT_TILES + ht ; block 256 (4 waves, 2M x 2H wave grid)
// per (e,ht): streams W_up/W_gate tile [64][2048] once from HBM; M-chunks of 128 slots.
__global__ __launch_bounds__(256) void k_upgate(
    const float* __restrict__ x, const float* __restrict__ Wu, const float* __restrict__ Wg,
    const int* __restrict__ counts, const int* __restrict__ basep,
    const int* __restrict__ tok, const float* __restrict__ wgt,
    unsigned short* __restrict__ hbuf) {
  int e  = blockIdx.x / HT_TILES;
  int ht = blockIdx.x % HT_TILES;
  int n_e = counts[e];
  if (n_e == 0) return;
  int base_e = basep[e];
  int nm = (n_e + 127) >> 7;

  __shared__ unsigned short xs[128*64];
  __shared__ unsigned short us[64*64];
  __shared__ unsigned short gs[64*64];
  __shared__ int   stok[128];
  __shared__ float swgt[128];

  int tid = threadIdx.x;
  int lane = tid & 63, wave = tid >> 6;
  int wm = wave >> 1, wh = wave & 1;
  const float* wu_base = Wu + ((size_t)e * DFFN + (size_t)ht * 64) * DMODEL;
  const float* wg_base = Wg + ((size_t)e * DFFN + (size_t)ht * 64) * DMODEL;

  for (int mch = 0; mch < nm; ++mch) {
    __syncthreads();
    if (tid < 128) {
      int r = mch*128 + tid;
      bool valid = r < n_e;
      stok[tid] = valid ? tok[base_e + r] : 0;
      swgt[tid] = valid ? wgt[base_e + r] : 0.f;
    }
    f32x4 ua[4][2], ga[4][2];
    #pragma unroll
    for (int t = 0; t < 4; ++t)
      #pragma unroll
      for (int j = 0; j < 2; ++j) {
        f32x4 z = {0.f, 0.f, 0.f, 0.f};
        ua[t][j] = z; ga[t][j] = z;
      }

    for (int kc = 0; kc < DMODEL/64; ++kc) {
      __syncthreads();
      // stage x rows (gathered by token) fp32->bf16
      #pragma unroll
      for (int i = 0; i < 8; ++i) {
        int idx = i*256 + tid;
        int row = idx >> 4, c4 = idx & 15;
        float4 v = *(const float4*)(x + (size_t)stok[row]*DMODEL + kc*64 + c4*4);
        st_bf16x4(xs, row, c4, v);
      }
      // stage W_up / W_gate tiles fp32->bf16
      #pragma unroll
      for (int i = 0; i < 4; ++i) {
        int idx = i*256 + tid;
        int row = idx >> 4, c4 = idx & 15;
        st_bf16x4(us, row, c4, *(const float4*)(wu_base + (size_t)row*DMODEL + kc*64 + c4*4));
        st_bf16x4(gs, row, c4, *(const float4*)(wg_base + (size_t)row*DMODEL + kc*64 + c4*4));
      }
      __syncthreads();
      #pragma unroll
      for (int kk = 0; kk < 2; ++kk) {
        int chunk = kk*4 + (lane >> 4);
        bf16x8 a[4], bu[2], bg[2];
        #pragma unroll
        for (int t = 0; t < 4; ++t) a[t] = ld_frag(xs, wm*64 + t*16 + (lane & 15), chunk);
        #pragma unroll
        for (int j = 0; j < 2; ++j) {
          bu[j] = ld_frag(us, wh*32 + j*16 + (lane & 15), chunk);
          bg[j] = ld_frag(gs, wh*32 + j*16 + (lane & 15), chunk);
        }
        #pragma unroll
        for (int t = 0; t < 4; ++t)
          #pragma unroll
          for (int j = 0; j < 2; ++j) {
            ua[t][j] = __builtin_amdgcn_mfma_f32_16x16x32_bf16(a[t], bu[j], ua[t][j], 0, 0, 0);
            ga[t][j] = __builtin_amdgcn_mfma_f32_16x16x32_bf16(a[t], bg[j], ga[t][j], 0, 0, 0);
          }
      }
    }
    // epilogue: h = silu(g)*u * gate_weight  -> bf16 h_buf
    #pragma unroll
    for (int t = 0; t < 4; ++t)
      #pragma unroll
      for (int j = 0; j < 2; ++j)
        #pragma unroll
        for (int r = 0; r < 4; ++r) {
          int ml = wm*64 + t*16 + (lane >> 4)*4 + r;
          if (mch*128 + ml < n_e) {
            float u = ua[t][j][r], g = ga[t][j][r];
            float hv = u * (g / (1.f + expf(-g))) * swgt[ml];
            int slot = base_e + mch*128 + ml;
            hbuf[(size_t)slot*DFFN + ht*64 + wh*32 + j*16 + (lane & 15)] = f2b_rne(hv);
          }
        }
  }
}

// ---------------- K5: down-proj GEMM -> per-slot partials (bf16) ----------------
// grid: e*CT_TILES + ct ; block 256 (4 waves)
__global__ __launch_bounds__(256) void k_down(
    const unsigned short* __restrict__ hbuf, const float* __restrict__ Wd,
    const int* __restrict__ counts, const int* __restrict__ basep,
    unsigned short* __restrict__ ypart) {
  int e  = blockIdx.x / CT_TILES;
  int ct = blockIdx.x % CT_TILES;
  int n_e = counts[e];
  if (n_e == 0) return;
  int base_e = basep[e];
  int nm = (n_e + 127) >> 7;

  __shared__ unsigned short hs[128*64];
  __shared__ unsigned short dw[64*64];

  int tid = threadIdx.x;
  int lane = tid & 63, wave = tid >> 6;
  int wm = wave >> 1, wh = wave & 1;
  const float* wd_base = Wd + ((size_t)e * DMODEL + (size_t)ct * 64) * DFFN;

  for (int mch = 0; mch < nm; ++mch) {
    f32x4 acc[4][2];
    #pragma unroll
    for (int t = 0; t < 4; ++t)
      #pragma unroll
      for (int j = 0; j < 2; ++j) { f32x4 z = {0.f,0.f,0.f,0.f}; acc[t][j] = z; }

    for (int hc = 0; hc < DFFN/64; ++hc) {
      __syncthreads();
      // stage h (already bf16): 128 rows x 64, 16B chunks, swizzled
      #pragma unroll
      for (int i = 0; i < 4; ++i) {
        int idx = i*256 + tid;          // 0..1023
        int row = idx >> 3, c8 = idx & 7;
        int slot = base_e + mch*128 + row;
        if (slot > 4095) slot = 4095;   // clamp (padded rows are masked at store)
        uint4 v = *(const uint4*)(hbuf + (size_t)slot*DFFN + hc*64 + c8*8);
        *(uint4*)(hs + row*64 + ((c8 ^ (row & 7)) * 8)) = v;
      }
      // stage W_down tile fp32->bf16
      #pragma unroll
      for (int i = 0; i < 4; ++i) {
        int idx = i*256 + tid;
        int row = idx >> 4, c4 = idx & 15;
        st_bf16x4(dw, row, c4, *(const float4*)(wd_base + (size_t)row*DFFN + hc*64 + c4*4));
      }
      __syncthreads();
      #pragma unroll
      for (int kk = 0; kk < 2; ++kk) {
        int chunk = kk*4 + (lane >> 4);
        bf16x8 a[4], b[2];
        #pragma unroll
        for (int t = 0; t < 4; ++t) a[t] = ld_frag(hs, wm*64 + t*16 + (lane & 15), chunk);
        #pragma unroll
        for (int j = 0; j < 2; ++j) b[j] = ld_frag(dw, wh*32 + j*16 + (lane & 15), chunk);
        #pragma unroll
        for (int t = 0; t < 4; ++t)
          #pragma unroll
          for (int j = 0; j < 2; ++j)
            acc[t][j] = __builtin_amdgcn_mfma_f32_16x16x32_bf16(a[t], b[j], acc[t][j], 0, 0, 0);
      }
    }
    // epilogue -> per-slot partial rows
    #pragma unroll
    for (int t = 0; t < 4; ++t)
      #pragma unroll
      for (int j = 0; j < 2; ++j)
        #pragma unroll
        for (int r = 0; r < 4; ++r) {
          int ml = wm*64 + t*16 + (lane >> 4)*4 + r;
          if (mch*128 + ml < n_e) {
            int slot = base_e + mch*128 + ml;
            ypart[(size_t)slot*DMODEL + ct*64 + wh*32 + j*16 + (lane & 15)] =
                f2b_rne(acc[t][j][r]);
          }
        }
  }
}

// ---------------- K6: combine 4 expert partials per token -> fp32 out ----------------
__global__ void k_combine(const unsigned short* __restrict__ ypart,
                          const int* __restrict__ slotnk, float* __restrict__ out) {
  int n = blockIdx.x, tid = threadIdx.x;
  int c0 = tid * 8;
  float acc[8] = {0.f,0.f,0.f,0.f,0.f,0.f,0.f,0.f};
  #pragma unroll
  for (int k = 0; k < TOPK; ++k) {
    int slot = slotnk[n*TOPK + k];
    uint4 v = *(const uint4*)(ypart + (size_t)slot*DMODEL + c0);
    const unsigned short* p = (const unsigned short*)&v;
    #pragma unroll
    for (int j = 0; j < 8; ++j) acc[j] += b2f(p[j]);
  }
  float4 o0 = {acc[0], acc[1], acc[2], acc[3]};
  float4 o1 = {acc[4], acc[5], acc[6], acc[7]};
  *(float4*)(out + (size_t)n*DMODEL + c0)     = o0;
  *(float4*)(out + (size_t)n*DMODEL + c0 + 4) = o1;
}

// ---------------- launcher ----------------
extern "C" void kernel_launch(void* const* d_in, const int* in_sizes, int n_in,
                              void* d_out, int out_size, void* d_ws, size_t ws_size,
                              hipStream_t stream) {
  const float* x     = (const float*)d_in[0];
  const float* W_up  = (const float*)d_in[1];
  const float* W_gt  = (const float*)d_in[2];
  const float* W_dn  = (const float*)d_in[3];
  const float* g_in  = (const float*)d_in[4];
  float* out = (float*)d_out;
  char* ws = (char*)d_ws;

  int*   counts = (int*)(ws + O_COUNTS);
  int*   basep  = (int*)(ws + O_BASE);
  int*   cursor = (int*)(ws + O_CURSOR);
  int*   topi   = (int*)(ws + O_TOPI);
  float* topw   = (float*)(ws + O_TOPW);
  int*   tok    = (int*)(ws + O_TOK);
  float* wgt    = (float*)(ws + O_WGT);
  int*   slotnk = (int*)(ws + O_SLOTNK);
  unsigned short* hbuf  = (unsigned short*)(ws + O_HBUF);
  unsigned short* ypart = (unsigned short*)(ws + O_YPART);

  k_zero   <<<1, 64, 0, stream>>>(counts, cursor);
  k_gate   <<<NTOK, 256, 0, stream>>>(x, g_in, topi, topw, counts);
  k_prefix <<<1, 64, 0, stream>>>(counts, basep);
  k_scatter<<<4, 256, 0, stream>>>(topi, topw, basep, cursor, tok, wgt, slotnk);
  k_upgate <<<EXP*HT_TILES, 256, 0, stream>>>(x, W_up, W_gt, counts, basep, tok, wgt, hbuf);
  k_down   <<<EXP*CT_TILES, 256, 0, stream>>>(hbuf, W_dn, counts, basep, ypart);
  k_combine<<<NTOK, 256, 0, stream>>>(ypart, slotnk, out);
}